// Round 1
// 64.580 us; speedup vs baseline: 1.0199x; 1.0199x over previous
//
#include <hip/hip_runtime.h>

// out[b] = bias + sum of w[tok] over UNIQUE tokens in column b of
// text[SEQ=200, BATCH=4096].
//
// R4: presence-bitmap dedup with atomicOr-return, fused gather.
//  - The CAS hash + slot-scan two-phase structure is replaced by ONE pass:
//    old = atomicOr(bitmap[tok>>5], bit); if bit was clear, add w[tok].
//    Exactly 1 LDS atomic per token (no probe loop), no 512-slot scan
//    (2.56x over-read), no LDS staging round-trip (tokens are used once).
//  - COLS=4 -> 25 KB LDS -> grid 1024 = 4 blocks/CU = 16 waves/CU (2x the
//    previous occupancy) for latency hiding; the kernel is pure
//    latency-bound (text 3.3 MB and w 200 KB are L2/L3 resident).
//  - 200*4 = 800 tokens/block over 256 threads: 3 unconditional + 1
//    masked (t<32) fully-unrolled iterations; all loads/atomics
//    independent -> max ILP.

#define SEQ    200
#define BATCH  4096
#define VOCAB  50000
#define COLS   4
#define WPC    1568   // ceil(50000/32)=1563 words/column, padded to %4

__global__ __launch_bounds__(256) void MNB_24111946400019_kernel(
    const int* __restrict__ text,
    const float* __restrict__ w,      // [50000]
    const float* __restrict__ bias,   // [1]
    float* __restrict__ out)          // [4096]
{
    __shared__ __align__(16) unsigned bm[COLS * WPC];  // 25,088 B
    __shared__ float partials[4][COLS];                // [wave][col]

    const int t  = threadIdx.x;
    const int c0 = blockIdx.x * COLS;
    const int j  = t & (COLS - 1);   // this thread's column, fixed

    // Zero the bitmaps: 1568 int4 stores / 256 threads = 6-7 each.
    {
        int4* p = (int4*)bm;
        const int4 z = make_int4(0, 0, 0, 0);
        for (int i = t; i < COLS * WPC / 4; i += 256) p[i] = z;
    }
    __syncthreads();

    // Thread t owns column j = t&3, rows s0, s0+64, s0+128 (+192 if t<32).
    // Consecutive lanes cover 4 cols x 16 rows per wave-load (16B segments).
    const int s0 = t >> 2;
    const int* tp = text + s0 * BATCH + c0 + j;
    const int tokA = tp[0];
    const int tokB = tp[64 * BATCH];
    const int tokC = tp[128 * BATCH];
    const int tokD = (t < 32) ? tp[192 * BATCH] : 0;   // 800 = 3*256 + 32

    unsigned* tb = bm + j * WPC;
    float sum = 0.0f;

    const unsigned bitA = 1u << (tokA & 31);
    const unsigned bitB = 1u << (tokB & 31);
    const unsigned bitC = 1u << (tokC & 31);
    // Independent atomics: dedup decision comes back in the old word.
    const unsigned oldA = atomicOr(&tb[tokA >> 5], bitA);
    const unsigned oldB = atomicOr(&tb[tokB >> 5], bitB);
    const unsigned oldC = atomicOr(&tb[tokC >> 5], bitC);
    if (!(oldA & bitA)) sum += w[tokA];
    if (!(oldB & bitB)) sum += w[tokB];
    if (!(oldC & bitC)) sum += w[tokC];
    if (t < 32) {
        const unsigned bitD = 1u << (tokD & 31);
        const unsigned oldD = atomicOr(&tb[tokD >> 5], bitD);
        if (!(oldD & bitD)) sum += w[tokD];
    }

    // Reduce across the 16 same-column lanes of each wave: same-j lanes
    // differ in thread-id bits 2..5 -> xor masks 4,8,16,32.
    #pragma unroll
    for (int off = 4; off <= 32; off <<= 1)
        sum += __shfl_xor(sum, off, 64);

    if ((t & 63) < COLS) partials[t >> 6][j] = sum;   // one lane per (wave,col)
    __syncthreads();

    if (t < COLS)
        out[c0 + t] = partials[0][t] + partials[1][t] + partials[2][t]
                    + partials[3][t] + bias[0];
}

extern "C" void kernel_launch(void* const* d_in, const int* in_sizes, int n_in,
                              void* d_out, int out_size, void* d_ws, size_t ws_size,
                              hipStream_t stream) {
    const int*   text = (const int*)d_in[0];    // [200*4096]
    const float* w    = (const float*)d_in[1];  // [50000]
    const float* bias = (const float*)d_in[2];  // [1]
    float* out = (float*)d_out;                 // [4096]

    MNB_24111946400019_kernel<<<BATCH / COLS, 256, 0, stream>>>(text, w, bias, out);
}